// Round 1
// baseline (122.035 us; speedup 1.0000x reference)
//
#include <hip/hip_runtime.h>
#include <hip/hip_bf16.h>

#define BB 4
#define NN 4096
#define DD 64
#define TJ 64
#define NT (NN / TJ)
#define SIGMA_INV 200.0f   // 1/0.005

typedef __attribute__((ext_vector_type(8))) short bf16x8;
typedef __attribute__((ext_vector_type(4))) float f32x4;

// workspace layout (bytes)
static constexpr size_t OFF_F1B = 0;                                    // bf16 [B][N][D]  2MB
static constexpr size_t OFF_F2B = OFF_F1B + (size_t)BB * NN * DD * 2;   // bf16 [B][N][D]  2MB
static constexpr size_t OFF_PP4 = OFF_F2B + (size_t)BB * NN * DD * 2;   // float4 [B][N]   256KB {px,py,pz,|p|^2} scaled
static constexpr size_t OFF_A2  = OFF_PP4 + (size_t)BB * NN * 16;       // f32 [B][N] |f1|^2
static constexpr size_t OFF_B2  = OFF_A2 + (size_t)BB * NN * 4;         // f32 [B][N] |f2|^2

__device__ __forceinline__ unsigned short f2bf(float x) {
  unsigned int u = __float_as_uint(x);
  u += 0x7FFFu + ((u >> 16) & 1u);   // round-to-nearest-even
  return (unsigned short)(u >> 16);
}

__device__ __forceinline__ void gl_lds16(const void* g, void* lds) {
  __builtin_amdgcn_global_load_lds((const __attribute__((address_space(1))) unsigned int*)g,
                                   (__attribute__((address_space(3))) unsigned int*)lds, 16, 0, 0);
}
__device__ __forceinline__ void gl_lds4(const void* g, void* lds) {
  __builtin_amdgcn_global_load_lds((const __attribute__((address_space(1))) unsigned int*)g,
                                   (__attribute__((address_space(3))) unsigned int*)lds, 4, 0, 0);
}

// ---------------- prep: fp32 -> bf16 for fea1/fea2 ----------------
__global__ void prep_convert(const float* __restrict__ f1, const float* __restrict__ f2,
                             unsigned short* __restrict__ f1b, unsigned short* __restrict__ f2b) {
  int i = blockIdx.x * blockDim.x + threadIdx.x;    // chunk of 4 elements
  if (i >= BB * NN * DD / 4) return;
  const float4* a4 = (const float4*)f1;
  const float4* b4 = (const float4*)f2;
  float4 a = a4[i], b = b4[i];
  ushort4 ua, ub;
  ua.x = f2bf(a.x); ua.y = f2bf(a.y); ua.z = f2bf(a.z); ua.w = f2bf(a.w);
  ub.x = f2bf(b.x); ub.y = f2bf(b.y); ub.z = f2bf(b.z); ub.w = f2bf(b.w);
  ((ushort4*)f1b)[i] = ua;
  ((ushort4*)f2b)[i] = ub;
}

// ---------------- prep: per-row norms + packed scaled points ----------------
__global__ void prep_rows(const float* __restrict__ pts, const float* __restrict__ f1,
                          const float* __restrict__ f2, float4* __restrict__ pp4,
                          float* __restrict__ a2, float* __restrict__ b2) {
  int row = blockIdx.x * blockDim.x + threadIdx.x;   // global row in [0, B*N)
  if (row >= BB * NN) return;
  const float4* r1 = (const float4*)(f1 + (size_t)row * DD);
  const float4* r2 = (const float4*)(f2 + (size_t)row * DD);
  float s1 = 0.f, s2 = 0.f;
#pragma unroll
  for (int c = 0; c < DD / 4; ++c) {
    float4 v = r1[c];
    s1 += v.x * v.x + v.y * v.y + v.z * v.z + v.w * v.w;
    float4 w = r2[c];
    s2 += w.x * w.x + w.y * w.y + w.z * w.z + w.w * w.w;
  }
  a2[row] = s1;
  b2[row] = s2;
  float px = pts[(size_t)row * 3 + 0] * SIGMA_INV;
  float py = pts[(size_t)row * 3 + 1] * SIGMA_INV;
  float pz = pts[(size_t)row * 3 + 2] * SIGMA_INV;
  pp4[row] = make_float4(px, py, pz, px * px + py * py + pz * pz);
}

// ---------------- reg loss from row norms ----------------
__global__ void reg_kernel(const float* __restrict__ a2, const float* __restrict__ b2,
                           float* __restrict__ out) {
  int b = blockIdx.x;
  __shared__ float red[256];
  float s = 0.f;
  for (int i = threadIdx.x; i < NN; i += 256) s += a2[b * NN + i] + b2[b * NN + i];
  red[threadIdx.x] = s;
  __syncthreads();
  for (int k = 128; k > 0; k >>= 1) {
    if (threadIdx.x < k) red[threadIdx.x] += red[threadIdx.x + k];
    __syncthreads();
  }
  if (threadIdx.x == 0) out[BB + b] = red[0] / (float)(NN * DD);
}

// ---------------- main fused ce kernel ----------------
// grid (NN/64, BB), block 256. Each wave owns 16 rows, streams all 4096 cols.
__global__ __launch_bounds__(256) void ce_kernel(
    const unsigned short* __restrict__ f1b, const unsigned short* __restrict__ f2b,
    const float4* __restrict__ pp4, const float* __restrict__ a2,
    const float* __restrict__ b2, const float* __restrict__ wts, float* __restrict__ out) {
  __shared__ unsigned short f2t[2][TJ * DD];   // 16KB, XOR-swizzled 16B chunks within 128B rows
  __shared__ float4 pt[2][TJ];                 // 2KB
  __shared__ float b2t[2][TJ];                 // 512B

  const int b = blockIdx.y;
  const int rowbase = blockIdx.x * 64;
  const int tid = threadIdx.x;
  const int wave = tid >> 6;
  const int lane = tid & 63;
  const int l15 = lane & 15;
  const int l4 = lane >> 4;

  // A fragments: f1 rows for this wave (constant across j loop)
  const unsigned short* f1row = f1b + ((size_t)(b * NN + rowbase + wave * 16 + l15)) * DD;
  bf16x8 af0 = *(const bf16x8*)(f1row + l4 * 8);
  bf16x8 af1 = *(const bf16x8*)(f1row + 32 + l4 * 8);

  // row-side constants for the 4 rows this lane's C-regs cover
  float prx[4], pry[4], prz[4], xp2[4], a2v[4];
#pragma unroll
  for (int r = 0; r < 4; ++r) {
    int rr = rowbase + wave * 16 + l4 * 4 + r;
    float4 p = pp4[b * NN + rr];
    prx[r] = p.x; pry[r] = p.y; prz[r] = p.z; xp2[r] = p.w;
    a2v[r] = a2[b * NN + rr];
  }

  float Mf[4], Zf[4], Zp[4], Sp[4];
#pragma unroll
  for (int r = 0; r < 4; ++r) { Mf[r] = -INFINITY; Zf[r] = 0.f; Zp[r] = 0.f; Sp[r] = 0.f; }

  auto stage = [&](int buf, int jt) {
    // f2 tile: 64 rows x 128B = 512 x 16B chunks; source pre-swizzled (rule #21)
    const char* gbase = (const char*)(f2b + ((size_t)(b * NN + jt * TJ)) * DD);
    {
      int c = tid;                      // chunk 0..255
      int r = c >> 3, s = c & 7;
      gl_lds16(gbase + r * 128 + (s ^ (r & 7)) * 16,
               (char*)&f2t[buf][0] + (wave * 64) * 16);
    }
    {
      int c = tid + 256;                // chunk 256..511
      int r = c >> 3, s = c & 7;
      gl_lds16(gbase + r * 128 + (s ^ (r & 7)) * 16,
               (char*)&f2t[buf][0] + (wave * 64 + 256) * 16);
    }
    if (wave == 0) {
      gl_lds16((const char*)(pp4 + (b * NN + jt * TJ + lane)), (char*)&pt[buf][0]);
    } else if (wave == 1) {
      gl_lds4((const char*)(b2 + (b * NN + jt * TJ + lane)), (char*)&b2t[buf][0]);
    }
  };

  stage(0, 0);

  for (int jt = 0; jt < NT; ++jt) {
    __syncthreads();   // drains vmcnt(0): staged tile published; prior reads done
    if (jt + 1 < NT) stage((jt + 1) & 1, jt + 1);
    const int cur = jt & 1;
#pragma unroll
    for (int s16 = 0; s16 < 4; ++s16) {
      const int jrow = s16 * 16 + l15;               // tile-local column index
      const unsigned short* base = &f2t[cur][jrow * DD];
      bf16x8 bf0 = *(const bf16x8*)(base + ((l4 ^ (jrow & 7)) * 8));
      bf16x8 bf1 = *(const bf16x8*)(base + (((4 + l4) ^ (jrow & 7)) * 8));
      f32x4 acc = {0.f, 0.f, 0.f, 0.f};
      acc = __builtin_amdgcn_mfma_f32_16x16x32_bf16(af0, bf0, acc, 0, 0, 0);
      acc = __builtin_amdgcn_mfma_f32_16x16x32_bf16(af1, bf1, acc, 0, 0, 0);
      float4 pj = pt[cur][jrow];
      float b2j = b2t[cur][jrow];
#pragma unroll
      for (int r = 0; r < 4; ++r) {
        float dotp = fmaf(prx[r], pj.x, fmaf(pry[r], pj.y, prz[r] * pj.z));
        float PD = fmaf(-2.f, dotp, xp2[r] + pj.w);
        float FDv = fmaf(-2.f, acc[r], a2v[r] + b2j);
        float ep = __expf(-PD);
        Zp[r] += ep;
        Sp[r] = fmaf(ep, FDv, Sp[r]);
        float sf = -FDv;
        if (sf > Mf[r]) { Zf[r] *= __expf(Mf[r] - sf); Mf[r] = sf; }
        Zf[r] += __expf(sf - Mf[r]);
      }
    }
  }

  // merge across the 16 lanes (same l4 group) that share rows
#pragma unroll
  for (int m = 1; m <= 8; m <<= 1) {
#pragma unroll
    for (int r = 0; r < 4; ++r) {
      float oM = __shfl_xor(Mf[r], m, 64);
      float oZ = __shfl_xor(Zf[r], m, 64);
      float M2 = fmaxf(Mf[r], oM);
      Zf[r] = Zf[r] * __expf(Mf[r] - M2) + oZ * __expf(oM - M2);
      Mf[r] = M2;
      Zp[r] += __shfl_xor(Zp[r], m, 64);
      Sp[r] += __shfl_xor(Sp[r], m, 64);
    }
  }

  if (l15 == 0) {
    float cs = 0.f;
#pragma unroll
    for (int r = 0; r < 4; ++r) {
      int rr = rowbase + wave * 16 + l4 * 4 + r;
      float w = wts[b * NN + rr];
      cs += w * (Sp[r] / Zp[r] + Mf[r] + __logf(Zf[r]));
    }
    atomicAdd(&out[b], cs);
  }
}

extern "C" void kernel_launch(void* const* d_in, const int* in_sizes, int n_in,
                              void* d_out, int out_size, void* d_ws, size_t ws_size,
                              hipStream_t stream) {
  const float* pts = (const float*)d_in[0];
  const float* f1  = (const float*)d_in[1];
  const float* f2  = (const float*)d_in[2];
  const float* wts = (const float*)d_in[3];
  float* out = (float*)d_out;
  char* ws = (char*)d_ws;

  unsigned short* f1b = (unsigned short*)(ws + OFF_F1B);
  unsigned short* f2b = (unsigned short*)(ws + OFF_F2B);
  float4* pp4 = (float4*)(ws + OFF_PP4);
  float* a2 = (float*)(ws + OFF_A2);
  float* b2 = (float*)(ws + OFF_B2);

  hipMemsetAsync(d_out, 0, 8 * sizeof(float), stream);

  prep_convert<<<(BB * NN * DD / 4 + 255) / 256, 256, 0, stream>>>(f1, f2, f1b, f2b);
  prep_rows<<<(BB * NN + 255) / 256, 256, 0, stream>>>(pts, f1, f2, pp4, a2, b2);
  reg_kernel<<<BB, 256, 0, stream>>>(a2, b2, out);

  dim3 grid(NN / 64, BB);
  ce_kernel<<<grid, 256, 0, stream>>>(f1b, f2b, pp4, a2, b2, wts, out);
}

// Round 2
// 49.190 us; speedup vs baseline: 2.4809x; 2.4809x over previous
//
#include <hip/hip_runtime.h>
#include <hip/hip_bf16.h>

#define BB 4
#define NN 4096
#define DD 64
#define TJ 64
#define CC 8                 // column chunks (grid.z)
#define CHUNK (NN / CC)      // 512 cols per block
#define NTC (CHUNK / TJ)     // 8 tiles per block
#define PSCALE 240.2244818f  // 200 * sqrt(log2(e)) : |p'i-p'j|^2 = PD*log2e
#define K2L 2.885390082f     // 2*log2(e)
#define NL2E -1.442695041f   // -log2(e)
#define LN2 0.6931471805599453f

typedef __attribute__((ext_vector_type(8))) short bf16x8;
typedef __attribute__((ext_vector_type(4))) float f32x4;

// workspace layout (bytes)
static constexpr size_t BN = (size_t)BB * NN;
static constexpr size_t OFF_F1B = 0;                          // bf16 [B][N][D]  2MB
static constexpr size_t OFF_F2B = OFF_F1B + BN * DD * 2;      // bf16 [B][N][D]  2MB
static constexpr size_t OFF_PP4 = OFF_F2B + BN * DD * 2;      // float4 [B][N] {p'x,p'y,p'z,|p'|^2}
static constexpr size_t OFF_NB2 = OFF_PP4 + BN * 16;          // f32 [B][N]  -|f2|^2*log2e
static constexpr size_t OFF_PZP = OFF_NB2 + BN * 4;           // f32 [C][B*N] partial Zp
static constexpr size_t OFF_PSP = OFF_PZP + CC * BN * 4;      // f32 [C][B*N] partial Spt
static constexpr size_t OFF_PZF = OFF_PSP + CC * BN * 4;      // f32 [C][B*N] partial Zf

__device__ __forceinline__ unsigned short f2bf(float x) {
  unsigned int u = __float_as_uint(x);
  u += 0x7FFFu + ((u >> 16) & 1u);   // round-to-nearest-even
  return (unsigned short)(u >> 16);
}

__device__ __forceinline__ void gl_lds16(const void* g, void* lds) {
  __builtin_amdgcn_global_load_lds((const __attribute__((address_space(1))) unsigned int*)g,
                                   (__attribute__((address_space(3))) unsigned int*)lds, 16, 0, 0);
}
__device__ __forceinline__ void gl_lds4(const void* g, void* lds) {
  __builtin_amdgcn_global_load_lds((const __attribute__((address_space(1))) unsigned int*)g,
                                   (__attribute__((address_space(3))) unsigned int*)lds, 4, 0, 0);
}

// ---------------- fused prep: bf16 convert + row norms + scaled points + reg ----
// grid B*N/64 = 256 blocks x 256 threads; block owns 64 rows.
__global__ __launch_bounds__(256) void prep_kernel(
    const float* __restrict__ pts, const float* __restrict__ f1,
    const float* __restrict__ f2, unsigned short* __restrict__ f1b,
    unsigned short* __restrict__ f2b, float4* __restrict__ pp4,
    float* __restrict__ nb2, float* __restrict__ out) {
  const int R0 = blockIdx.x * 64;
  const int t = threadIdx.x;
  const float4* f1v = (const float4*)(f1 + (size_t)R0 * DD);
  const float4* f2v = (const float4*)(f2 + (size_t)R0 * DD);
  ushort4* o1 = (ushort4*)(f1b + (size_t)R0 * DD);
  ushort4* o2 = (ushort4*)(f2b + (size_t)R0 * DD);
  float regsum = 0.f;
#pragma unroll
  for (int p = 0; p < 4; ++p) {
    int c = t + p * 256;                 // float4-chunk in [0,1024); row = R0 + c/16
    float4 a = f1v[c], b = f2v[c];
    ushort4 ua, ub;
    ua.x = f2bf(a.x); ua.y = f2bf(a.y); ua.z = f2bf(a.z); ua.w = f2bf(a.w);
    ub.x = f2bf(b.x); ub.y = f2bf(b.y); ub.z = f2bf(b.z); ub.w = f2bf(b.w);
    o1[c] = ua; o2[c] = ub;
    float s1 = a.x * a.x + a.y * a.y + a.z * a.z + a.w * a.w;
    float s2 = b.x * b.x + b.y * b.y + b.z * b.z + b.w * b.w;
    regsum += s1 + s2;
    float s2r = s2;
#pragma unroll
    for (int m = 1; m <= 8; m <<= 1) s2r += __shfl_xor(s2r, m, 64);
    if ((t & 15) == 0) nb2[R0 + (c >> 4)] = NL2E * s2r;
  }
  if (t < 64) {
    int row = R0 + t;
    float px = pts[row * 3 + 0] * PSCALE;
    float py = pts[row * 3 + 1] * PSCALE;
    float pz = pts[row * 3 + 2] * PSCALE;
    pp4[row] = make_float4(px, py, pz, fmaf(px, px, fmaf(py, py, pz * pz)));
  }
  __shared__ float red[256];
  red[t] = regsum;
  __syncthreads();
  for (int k = 128; k > 0; k >>= 1) {
    if (t < k) red[t] += red[t + k];
    __syncthreads();
  }
  if (t == 0) atomicAdd(&out[BB + R0 / NN], red[0] * (1.f / ((float)NN * DD)));
}

// ---------------- main fused ce kernel ----------------
// grid (NN/64, BB, CC), block 256. Wave owns 16 rows x 512 cols (8 tiles).
__global__ __launch_bounds__(256) void ce_kernel(
    const unsigned short* __restrict__ f1b, const unsigned short* __restrict__ f2b,
    const float4* __restrict__ pp4, const float* __restrict__ nb2g,
    float* __restrict__ pZp, float* __restrict__ pSp, float* __restrict__ pZf) {
  __shared__ unsigned short f2t[2][TJ * DD];   // 16KB, XOR-swizzled 16B chunks in 128B rows
  __shared__ float4 pt[2][TJ];                 // 2KB
  __shared__ float b2t[2][TJ];                 // 512B

  const int b = blockIdx.y;
  const int ck = blockIdx.z;
  const int rowbase = blockIdx.x * 64;
  const int tid = threadIdx.x;
  const int wave = tid >> 6;
  const int lane = tid & 63;
  const int l15 = lane & 15;
  const int l4 = lane >> 4;

  // A fragments: f1 rows for this wave (constant across j loop)
  const unsigned short* f1row = f1b + ((size_t)(b * NN + rowbase + wave * 16 + l15)) * DD;
  bf16x8 af0 = *(const bf16x8*)(f1row + l4 * 8);
  bf16x8 af1 = *(const bf16x8*)(f1row + 32 + l4 * 8);

  float prx[4], pry[4], prz[4], xp2[4];
#pragma unroll
  for (int r = 0; r < 4; ++r) {
    int rr = rowbase + wave * 16 + l4 * 4 + r;
    float4 p = pp4[b * NN + rr];
    prx[r] = p.x; pry[r] = p.y; prz[r] = p.z; xp2[r] = p.w;
  }

  float Zp[4], Sp[4], Zf[4];
#pragma unroll
  for (int r = 0; r < 4; ++r) { Zp[r] = 0.f; Sp[r] = 0.f; Zf[r] = 0.f; }

  auto stage = [&](int buf, int col0) {   // col0: batch-local column of tile start
    const char* gbase = (const char*)(f2b + ((size_t)(b * NN + col0)) * DD);
    {
      int r = tid >> 3, s = tid & 7;
      gl_lds16(gbase + r * 128 + (s ^ (r & 7)) * 16, (char*)&f2t[buf][0] + wave * 1024);
    }
    {
      int c = tid + 256;
      int r = c >> 3, s = c & 7;
      gl_lds16(gbase + r * 128 + (s ^ (r & 7)) * 16, (char*)&f2t[buf][0] + wave * 1024 + 4096);
    }
    if (wave == 0) {
      gl_lds16((const char*)(pp4 + (b * NN + col0 + lane)), (char*)&pt[buf][0]);
    } else if (wave == 1) {
      gl_lds4((const char*)(nb2g + (b * NN + col0 + lane)), (char*)&b2t[buf][0]);
    }
  };

  const int colbase = ck * CHUNK;
  stage(0, colbase);

  // s16-invariant swizzled LDS offsets (s16 enters as ds_read immediate)
  const int swz0 = ((l4 ^ (l15 & 7)) << 4);
  const int swz1 = (((l4 ^ 4) ^ (l15 & 7)) << 4);

  for (int jt = 0; jt < NTC; ++jt) {
    __syncthreads();   // drains vmcnt(0): staged tile published; prior reads done
    if (jt + 1 < NTC) stage((jt + 1) & 1, colbase + (jt + 1) * TJ);
    const int cur = jt & 1;
    const char* f2c = (const char*)f2t + cur * 8192 + l15 * 128;
#pragma unroll
    for (int s16 = 0; s16 < 4; ++s16) {
      bf16x8 bf0 = *(const bf16x8*)(f2c + swz0 + s16 * 2048);
      bf16x8 bf1 = *(const bf16x8*)(f2c + swz1 + s16 * 2048);
      f32x4 acc = {0.f, 0.f, 0.f, 0.f};
      acc = __builtin_amdgcn_mfma_f32_16x16x32_bf16(af0, bf0, acc, 0, 0, 0);
      acc = __builtin_amdgcn_mfma_f32_16x16x32_bf16(af1, bf1, acc, 0, 0, 0);
      const int jrow = s16 * 16 + l15;
      float4 pj = pt[cur][jrow];
      float nb2j = b2t[cur][jrow];
      float t2[4], PD2[4];
#pragma unroll
      for (int r = 0; r < 4; ++r) {
        float dotp = fmaf(prx[r], pj.x, fmaf(pry[r], pj.y, prz[r] * pj.z));
        PD2[r] = fmaf(-2.f, dotp, xp2[r] + pj.w);          // PD * log2(e)
        t2[r] = fmaf(K2L, acc[r], nb2j);                   // (2*dot - b2) * log2(e)
        Zf[r] += __builtin_amdgcn_exp2f(t2[r]);
      }
      float mn = fminf(fminf(PD2[0], PD2[1]), fminf(PD2[2], PD2[3]));
      if (mn < 126.f) {   // else all four exp2(-PD2) flush to 0 exactly
#pragma unroll
        for (int r = 0; r < 4; ++r) {
          float ep = __builtin_amdgcn_exp2f(-PD2[r]);
          Zp[r] += ep;
          Sp[r] = fmaf(ep, t2[r], Sp[r]);
        }
      }
    }
  }

  // merge across the 16 lanes (same l4 group) that share rows
#pragma unroll
  for (int m = 1; m <= 8; m <<= 1) {
#pragma unroll
    for (int r = 0; r < 4; ++r) {
      Zp[r] += __shfl_xor(Zp[r], m, 64);
      Sp[r] += __shfl_xor(Sp[r], m, 64);
      Zf[r] += __shfl_xor(Zf[r], m, 64);
    }
  }

  if (l15 == 0) {
    size_t base = (size_t)ck * BN + b * NN + rowbase + wave * 16 + l4 * 4;
#pragma unroll
    for (int r = 0; r < 4; ++r) {
      pZp[base + r] = Zp[r];
      pSp[base + r] = Sp[r];
      pZf[base + r] = Zf[r];
    }
  }
}

// ---------------- finalize: merge chunks, compute ce per row, reduce ----------
__global__ __launch_bounds__(256) void finalize_kernel(
    const float* __restrict__ pZp, const float* __restrict__ pSp,
    const float* __restrict__ pZf, const float* __restrict__ wts,
    float* __restrict__ out) {
  const int i = blockIdx.x * 256 + threadIdx.x;    // row in [0, B*N)
  float Zp = 0.f, Sp = 0.f, Zf = 0.f;
#pragma unroll
  for (int c = 0; c < CC; ++c) {
    Zp += pZp[(size_t)c * BN + i];
    Sp += pSp[(size_t)c * BN + i];
    Zf += pZf[(size_t)c * BN + i];
  }
  // ce_i = w_i * ln2 * (log2(Zf_i) - Sp_i/Zp_i)   (the |f1|^2 terms cancel)
  float ce = wts[i] * (LN2 * (__builtin_amdgcn_logf(Zf) - Sp / Zp));
  __shared__ float red[256];
  red[threadIdx.x] = ce;
  __syncthreads();
  for (int k = 128; k > 0; k >>= 1) {
    if (threadIdx.x < k) red[threadIdx.x] += red[threadIdx.x + k];
    __syncthreads();
  }
  if (threadIdx.x == 0) atomicAdd(&out[i / NN], red[0]);
}

extern "C" void kernel_launch(void* const* d_in, const int* in_sizes, int n_in,
                              void* d_out, int out_size, void* d_ws, size_t ws_size,
                              hipStream_t stream) {
  const float* pts = (const float*)d_in[0];
  const float* f1  = (const float*)d_in[1];
  const float* f2  = (const float*)d_in[2];
  const float* wts = (const float*)d_in[3];
  float* out = (float*)d_out;
  char* ws = (char*)d_ws;

  unsigned short* f1b = (unsigned short*)(ws + OFF_F1B);
  unsigned short* f2b = (unsigned short*)(ws + OFF_F2B);
  float4* pp4 = (float4*)(ws + OFF_PP4);
  float* nb2 = (float*)(ws + OFF_NB2);
  float* pZp = (float*)(ws + OFF_PZP);
  float* pSp = (float*)(ws + OFF_PSP);
  float* pZf = (float*)(ws + OFF_PZF);

  hipMemsetAsync(d_out, 0, 8 * sizeof(float), stream);

  prep_kernel<<<BN / 64, 256, 0, stream>>>(pts, f1, f2, f1b, f2b, pp4, nb2, out);

  dim3 grid(NN / 64, BB, CC);
  ce_kernel<<<grid, 256, 0, stream>>>(f1b, f2b, pp4, nb2, pZp, pSp, pZf);

  finalize_kernel<<<BN / 256, 256, 0, stream>>>(pZp, pSp, pZf, wts, out);
}